// Round 1
// baseline (29.076 us; speedup 1.0000x reference)
//
#include <hip/hip_runtime.h>

// Problem constants (from reference): tensors (1024, 256, 16) fp32,
// WINDOW=5, STRIDES=1 -> starts = 0..251 (S=252), F=16 -> 120 triu pairs.
// out[b][p][s], p in np.triu_indices(16,1) row-major order.
#define NB 1024
#define NT 256
#define NF 16
#define NW 5
#define NS 252   // NT - NW + 1
#define NPAIR 120
#define EPS 1e-5f

__global__ __launch_bounds__(256) void ts_corr_kernel(const float* __restrict__ in,
                                                      float* __restrict__ out) {
    const int b = blockIdx.x;
    const int s = threadIdx.x;
    if (s >= NS) return;

    // Load the 5x16 window into registers (vectorized float4 loads).
    const float* row0 = in + ((size_t)b * NT + s) * NF;
    float x[NW][NF];
    #pragma unroll
    for (int w = 0; w < NW; ++w) {
        const float4* r4 = reinterpret_cast<const float4*>(row0 + w * NF);
        #pragma unroll
        for (int q = 0; q < 4; ++q) {
            float4 v = r4[q];
            x[w][q * 4 + 0] = v.x;
            x[w][q * 4 + 1] = v.y;
            x[w][q * 4 + 2] = v.z;
            x[w][q * 4 + 3] = v.w;
        }
    }

    // Per-feature mean and 1/(std+eps), std with ddof=1 (divide by W-1=4).
    float mean[NF], rstd[NF];
    #pragma unroll
    for (int i = 0; i < NF; ++i) {
        float sum = 0.f, sq = 0.f;
        #pragma unroll
        for (int w = 0; w < NW; ++w) {
            sum += x[w][i];
            sq  += x[w][i] * x[w][i];
        }
        float m = sum * (1.0f / NW);
        mean[i] = m;
        float var = (sq - (float)NW * m * m) * (1.0f / (NW - 1));
        var = fmaxf(var, 0.0f);
        rstd[i] = 1.0f / (sqrtf(var) + EPS);
    }

    // 120 upper-triangle pairs; write out[b][p][s] (s fastest -> coalesced
    // across the wave for each p).
    float* outb = out + (size_t)b * NPAIR * NS + s;
    int p = 0;
    #pragma unroll
    for (int i = 0; i < NF; ++i) {
        #pragma unroll
        for (int j = i + 1; j < NF; ++j) {
            float sxy = 0.f;
            #pragma unroll
            for (int w = 0; w < NW; ++w) sxy += x[w][i] * x[w][j];
            float cov = sxy * (1.0f / NW) - mean[i] * mean[j];
            outb[(size_t)p * NS] = cov * rstd[i] * rstd[j];
            ++p;
        }
    }
}

extern "C" void kernel_launch(void* const* d_in, const int* in_sizes, int n_in,
                              void* d_out, int out_size, void* d_ws, size_t ws_size,
                              hipStream_t stream) {
    const float* in = (const float*)d_in[0];
    float* out = (float*)d_out;
    dim3 grid(NB);
    dim3 block(256);
    ts_corr_kernel<<<grid, block, 0, stream>>>(in, out);
}